// Round 5
// baseline (44.321 us; speedup 1.0000x reference)
//
#include <hip/hip_runtime.h>
#include <math.h>

// Sizes fixed by the reference
#define NB 2
#define NN 256
#define KD 16
#define VV 32000
#define EPS_SELF 1e-8f
#define EPS_AL   1e-6f
#define NNODES (NB*NN)   // 512

#define CE_ROWS 8
#define CE_CH   32
#define CE_CHUNK (VV/CE_CH)   // 1000

// ws layout (float offsets)
#define OFF_MT  0                       // 512*16  rotated means
#define OFF_SH  (NNODES*16)             // 512*256 Shat = E^T Sigma E + eps I (symmetric)
#define OFF_P   (OFF_SH + NNODES*256)   // 512*256 P = (Shat)^-1 (symmetric)
#define OFF_LD  (OFF_P + NNODES*256)    // 512     2*sum log(sqrt(d_k)+eps)
#define OFF_KLS (OFF_LD + NNODES)       // 512     per-node kl_self
#define OFF_AP  (OFF_KLS + NNODES)      // 512     align tile partials
#define OFF_CEP (OFF_AP + NNODES)       // 512*32  ce chunk partial sums
#define OFF_CNT (OFF_CEP + NNODES*CE_CH) // 1      completion counter (uint)
#define WS_FLOATS (OFF_CNT + 4)

// wave-synchronous LDS visibility: whole-wave ds_write completes before
// subsequent ds_read (DS pipe is in-order per wave); just drain lgkm.
#define WAVE_SYNC() asm volatile("s_waitcnt lgkmcnt(0)" ::: "memory")

__device__ __forceinline__ void ld4(float* dst, const float4 v) {
  dst[0] = v.x; dst[1] = v.y; dst[2] = v.z; dst[3] = v.w;
}

__device__ __forceinline__ float dot16a(const float* a, const float* b) {
  float acc = 0.f;
  #pragma unroll
  for (int j = 0; j < 16; ++j) acc = fmaf(a[j], b[j], acc);
  return acc;
}

// In-register Gauss-Jordan inverse of 16x16 via shuffles.
// Lane (g=l>>4, c=l&15) holds aq[q] = A[4g+q][c]. Optional logdet (sum log pivots).
__device__ __forceinline__ void gj16(float aq[4], const int g, const int c, float* ldacc) {
  #pragma unroll
  for (int k = 0; k < 16; ++k) {
    float d    = __shfl(aq[k & 3], ((k >> 2) << 4) | k);
    float rowk = __shfl(aq[k & 3], ((k >> 2) << 4) | c);
    float ck[4];
    #pragma unroll
    for (int q = 0; q < 4; ++q) ck[q] = __shfl(aq[q], (g << 4) | k);
    if (ldacc) *ldacc += logf(d);
    float dinv = 1.f / d;
    #pragma unroll
    for (int q = 0; q < 4; ++q) {
      int r = 4*g + q;
      float vgen = fmaf(-ck[q] * dinv, rowk, aq[q]);
      aq[q] = (r == k) ? ((c == k) ? dinv : aq[q] * dinv)
                       : ((c == k) ? (-ck[q] * dinv) : vgen);
    }
  }
}

// Pivot-only Gaussian elimination: returns logdet-style sum over pivots.
// QUIRK=0: sum log(d). QUIRK=1: sum 2*log(sqrt(d)+EPS_AL) (ref Cholesky-diag quirk).
template<int QUIRK>
__device__ __forceinline__ float ge16_logdet(float aq[4], const int g, const int c) {
  float ld = 0.f;
  #pragma unroll
  for (int k = 0; k < 16; ++k) {
    float d    = __shfl(aq[k & 3], ((k >> 2) << 4) | k);
    float rowk = __shfl(aq[k & 3], ((k >> 2) << 4) | c);
    float ck[4];
    #pragma unroll
    for (int q = 0; q < 4; ++q) ck[q] = __shfl(aq[q], (g << 4) | k);
    ld += QUIRK ? 2.f * logf(sqrtf(d) + EPS_AL) : logf(d);
    float dinv = 1.f / d;
    #pragma unroll
    for (int q = 0; q < 4; ++q) {
      int r = 4*g + q;
      float upd = fmaf(-ck[q] * dinv, rowk, aq[q]);
      aq[q] = (r > k && c > k) ? upd : aq[q];
    }
  }
  return ld;
}

#define DOT16(q0,q1,q2,q3,A) \
  fmaf(q0.x,A[0],fmaf(q0.y,A[1],fmaf(q0.z,A[2],fmaf(q0.w,A[3], \
  fmaf(q1.x,A[4],fmaf(q1.y,A[5],fmaf(q1.z,A[6],fmaf(q1.w,A[7], \
  fmaf(q2.x,A[8],fmaf(q2.y,A[9],fmaf(q2.z,A[10],fmaf(q2.w,A[11], \
  fmaf(q3.x,A[12],fmaf(q3.y,A[13],fmaf(q3.z,A[14],q3.w*A[15])))))))))))))))

// ---------------- Kernel A: prep (blocks 0..255) UNION ce1 (blocks 256..2303) ----------------
__global__ __launch_bounds__(256) void fusedA_kernel(
    const float* __restrict__ mu, const float* __restrict__ Sigma,
    const float* __restrict__ phi, const float* __restrict__ mu_prior,
    const float* __restrict__ Sigma_prior, const float* __restrict__ gen,
    const float* __restrict__ W, float* __restrict__ ws)
{
  __shared__ __align__(16) float smem[4][980];   // prep: per-wave scratch; ce1: reuse
  const int tid = threadIdx.x;
  const int bid = blockIdx.x;

  if (bid < 256) {
    if (bid == 0 && tid == 0) *(unsigned*)(ws + OFF_CNT) = 0u;  // reset B's counter
    const int w = tid >> 6, l = tid & 63;
    const int g = l >> 4, c = l & 15;
    const int unit = bid * 4 + w;
    const int role = unit & 1, node = unit >> 1;
    float* COLp = &smem[w][0];
    float* ROWp = &smem[w][320];
    float* AUXp = &smem[w][640];

    if (role == 0) {
      float phis[16];
      {
        const float4* p4 = (const float4*)(phi + node*16);
        ld4(phis, p4[0]); ld4(phis+4, p4[1]); ld4(phis+8, p4[2]); ld4(phis+12, p4[3]);
      }
      // X[4g+q][c] = 0.125*sum_a phi_a G[a][4g+q][c];  G[a][r][c] = -gen[a][c][r] (exact skew)
      float x[4] = {0.f, 0.f, 0.f, 0.f};
      #pragma unroll
      for (int aa = 0; aa < 16; ++aa) {
        float4 gq = *(const float4*)(gen + aa*256 + c*16 + 4*g);
        x[0] = fmaf(phis[aa], gq.x, x[0]);
        x[1] = fmaf(phis[aa], gq.y, x[1]);
        x[2] = fmaf(phis[aa], gq.z, x[2]);
        x[3] = fmaf(phis[aa], gq.w, x[3]);
      }
      #pragma unroll
      for (int q = 0; q < 4; ++q) x[q] *= -0.125f;

      #pragma unroll
      for (int q = 0; q < 4; ++q) ROWp[(4*g+q)*20 + c] = x[q];
      WAVE_SYNC();
      float Mrow[4][16];
      #pragma unroll
      for (int q = 0; q < 4; ++q)
        #pragma unroll
        for (int j4 = 0; j4 < 4; ++j4)
          ld4(&Mrow[q][4*j4], *(const float4*)&ROWp[(4*g+q)*20 + 4*j4]);

      // Horner order 8
      float t[4];
      #pragma unroll
      for (int q = 0; q < 4; ++q) t[q] = ((4*g+q) == c ? 1.f : 0.f) + x[q]*0.125f;
      for (int k = 7; k >= 1; --k) {
        *(float4*)&COLp[c*20 + 4*g] = make_float4(t[0], t[1], t[2], t[3]);
        WAVE_SYNC();
        float T[16];
        #pragma unroll
        for (int j4 = 0; j4 < 4; ++j4) ld4(&T[4*j4], *(const float4*)&COLp[c*20 + 4*j4]);
        #pragma unroll
        for (int q = 0; q < 4; ++q)
          t[q] = ((4*g+q) == c ? 1.f : 0.f) + dot16a(Mrow[q], T) / (float)k;
      }
      // 3 squarings -> E
      for (int s = 0; s < 3; ++s) {
        *(float4*)&COLp[c*20 + 4*g] = make_float4(t[0], t[1], t[2], t[3]);
        #pragma unroll
        for (int q = 0; q < 4; ++q) ROWp[(4*g+q)*20 + c] = t[q];
        WAVE_SYNC();
        float T[16];
        #pragma unroll
        for (int j4 = 0; j4 < 4; ++j4) ld4(&T[4*j4], *(const float4*)&COLp[c*20 + 4*j4]);
        float nt[4];
        #pragma unroll
        for (int q = 0; q < 4; ++q) {
          float acc = 0.f;
          #pragma unroll
          for (int j4 = 0; j4 < 4; ++j4) {
            float4 rv = *(const float4*)&ROWp[(4*g+q)*20 + 4*j4];
            acc = fmaf(rv.x, T[4*j4+0], acc);
            acc = fmaf(rv.y, T[4*j4+1], acc);
            acc = fmaf(rv.z, T[4*j4+2], acc);
            acc = fmaf(rv.w, T[4*j4+3], acc);
          }
          nt[q] = acc;
        }
        #pragma unroll
        for (int q = 0; q < 4; ++q) t[q] = nt[q];
      }
      *(float4*)&COLp[c*20 + 4*g] = make_float4(t[0], t[1], t[2], t[3]);
      WAVE_SYNC();
      float Ecol[16];
      #pragma unroll
      for (int j4 = 0; j4 < 4; ++j4) ld4(&Ecol[4*j4], *(const float4*)&COLp[c*20 + 4*j4]);

      // W1 = Sigma * E
      float w1q[4];
      #pragma unroll
      for (int q = 0; q < 4; ++q) {
        float S[16];
        const float4* s4 = (const float4*)(Sigma + node*256 + (4*g+q)*16);
        ld4(S, s4[0]); ld4(S+4, s4[1]); ld4(S+8, s4[2]); ld4(S+12, s4[3]);
        w1q[q] = dot16a(S, Ecol);
      }
      *(float4*)&AUXp[c*20 + 4*g] = make_float4(w1q[0], w1q[1], w1q[2], w1q[3]);
      WAVE_SYNC();
      float W1c[16];
      #pragma unroll
      for (int j4 = 0; j4 < 4; ++j4) ld4(&W1c[4*j4], *(const float4*)&AUXp[c*20 + 4*j4]);

      // Shat = E^T W1 + eps I
      float sh[4];
      #pragma unroll
      for (int q = 0; q < 4; ++q) {
        float Er[16];
        #pragma unroll
        for (int j4 = 0; j4 < 4; ++j4) ld4(&Er[4*j4], *(const float4*)&COLp[(4*g+q)*20 + 4*j4]);
        sh[q] = dot16a(Er, W1c) + ((4*g+q) == c ? EPS_AL : 0.f);
      }
      *(float4*)(ws + OFF_SH + node*256 + c*16 + 4*g) = make_float4(sh[0], sh[1], sh[2], sh[3]);

      // mt = E^T mu
      {
        float muv[16];
        const float4* m4 = (const float4*)(mu + node*16);
        ld4(muv, m4[0]); ld4(muv+4, m4[1]); ld4(muv+8, m4[2]); ld4(muv+12, m4[3]);
        float mt = dot16a(Ecol, muv);
        if (g == 0) ws[OFF_MT + node*16 + c] = mt;
      }
      // P = inv(Shat)
      gj16(sh, g, c, (float*)nullptr);
      *(float4*)(ws + OFF_P + node*256 + c*16 + 4*g) = make_float4(sh[0], sh[1], sh[2], sh[3]);
    } else {
      // ---------- V_self + align logdet ----------
      float sp[4];
      {
        float4 v = *(const float4*)(Sigma_prior + node*256 + c*16 + 4*g);
        sp[0] = v.x + ((4*g+0 == c) ? EPS_SELF : 0.f);
        sp[1] = v.y + ((4*g+1 == c) ? EPS_SELF : 0.f);
        sp[2] = v.z + ((4*g+2 == c) ? EPS_SELF : 0.f);
        sp[3] = v.w + ((4*g+3 == c) ? EPS_SELF : 0.f);
      }
      float ldSp = 0.f;
      gj16(sp, g, c, &ldSp);

      float dmur[4], dmuc;
      {
        float4 a = *(const float4*)(mu_prior + node*16 + 4*g);
        float4 b = *(const float4*)(mu + node*16 + 4*g);
        dmur[0] = a.x - b.x; dmur[1] = a.y - b.y; dmur[2] = a.z - b.z; dmur[3] = a.w - b.w;
        dmuc = mu_prior[node*16 + c] - mu[node*16 + c];
      }
      float4 sv = *(const float4*)(Sigma + node*256 + c*16 + 4*g);
      float val = 0.f;
      {
        float s0 = sv.x + ((4*g+0 == c) ? EPS_SELF : 0.f);
        float s1 = sv.y + ((4*g+1 == c) ? EPS_SELF : 0.f);
        float s2 = sv.z + ((4*g+2 == c) ? EPS_SELF : 0.f);
        float s3 = sv.w + ((4*g+3 == c) ? EPS_SELF : 0.f);
        val = fmaf(sp[0], s0 + dmur[0]*dmuc, val);
        val = fmaf(sp[1], s1 + dmur[1]*dmuc, val);
        val = fmaf(sp[2], s2 + dmur[2]*dmuc, val);
        val = fmaf(sp[3], s3 + dmur[3]*dmuc, val);
      }
      #pragma unroll
      for (int o = 32; o; o >>= 1) val += __shfl_xor(val, o);

      float sq[4];
      sq[0] = sv.x + ((4*g+0 == c) ? EPS_SELF : 0.f);
      sq[1] = sv.y + ((4*g+1 == c) ? EPS_SELF : 0.f);
      sq[2] = sv.z + ((4*g+2 == c) ? EPS_SELF : 0.f);
      sq[3] = sv.w + ((4*g+3 == c) ? EPS_SELF : 0.f);
      float ldSq = ge16_logdet<0>(sq, g, c);
      float sg[4];
      sg[0] = sv.x + ((4*g+0 == c) ? EPS_AL : 0.f);
      sg[1] = sv.y + ((4*g+1 == c) ? EPS_AL : 0.f);
      sg[2] = sv.z + ((4*g+2 == c) ? EPS_AL : 0.f);
      sg[3] = sv.w + ((4*g+3 == c) ? EPS_AL : 0.f);
      float ldq = ge16_logdet<1>(sg, g, c);
      if (l == 0) {
        ws[OFF_KLS + node] = 0.5f * (val - 16.f + ldSp - ldSq);
        ws[OFF_LD + node]  = ldq;
      }
    }
  } else {
    // ---------- ce1: CE partial sums ----------
    const int idx = bid - 256;
    const int grp = idx & 63;       // row group
    const int ch  = idx >> 6;       // vocab chunk
    const int row0 = grp * CE_ROWS;
    float* mu_s = &smem[0][0];      // 128
    float* wred = &smem[0][128];    // 32

    if (tid < CE_ROWS*16) mu_s[tid] = mu[row0*16 + tid];
    __syncthreads();

    float A[CE_ROWS][16];
    #pragma unroll
    for (int r = 0; r < CE_ROWS; ++r)
      #pragma unroll
      for (int k = 0; k < 16; ++k) A[r][k] = mu_s[r*16+k];

    float acc[CE_ROWS];
    #pragma unroll
    for (int r = 0; r < CE_ROWS; ++r) acc[r] = 0.f;

    const float4* W4 = (const float4*)W;
    const int v0 = ch * CE_CHUNK;
    for (int v = v0 + tid; v < v0 + CE_CHUNK; v += 256) {
      float4 q0 = W4[v*4+0], q1 = W4[v*4+1], q2 = W4[v*4+2], q3 = W4[v*4+3];
      #pragma unroll
      for (int r = 0; r < CE_ROWS; ++r) {
        float lg = DOT16(q0,q1,q2,q3,A[r]);
        acc[r] += __expf(lg);   // logits O(0.4): direct exp-sum fp32-safe
      }
    }
    // in-wave butterfly, then cross-wave via LDS
    #pragma unroll
    for (int r = 0; r < CE_ROWS; ++r)
      #pragma unroll
      for (int o = 32; o; o >>= 1) acc[r] += __shfl_xor(acc[r], o);
    const int w = tid >> 6, l = tid & 63;
    if (l == 0) {
      #pragma unroll
      for (int r = 0; r < CE_ROWS; ++r) wred[w*CE_ROWS + r] = acc[r];
    }
    __syncthreads();
    if (tid < CE_ROWS)
      ws[OFF_CEP + (row0 + tid)*CE_CH + ch] =
          wred[tid] + wred[CE_ROWS + tid] + wred[2*CE_ROWS + tid] + wred[3*CE_ROWS + tid];
  }
}

// ---------------- Kernel B: pairwise V_align + last-block final reduce ----------------
#define PSTR 260
__global__ __launch_bounds__(256) void alignB_kernel(
    const float* __restrict__ beta, const float* __restrict__ mu,
    const float* __restrict__ W, const int* __restrict__ targets,
    float* __restrict__ ws, float* __restrict__ out)
{
  __shared__ __align__(16) float ShI[16*PSTR];
  __shared__ __align__(16) float PJ[16*PSTR];
  __shared__ float mtI[256], mtJ[256], ldI[16], ldJ[16], red[4];
  __shared__ int lastflag;
  const int tid = threadIdx.x;
  const int ti = tid & 15, tj = tid >> 4;
  const int bx = blockIdx.x & 15, by = (blockIdx.x >> 4) & 15, bz = blockIdx.x >> 8;
  const int nodeI0 = bz*256 + by*16, nodeJ0 = bz*256 + bx*16;

  for (int idx = tid; idx < 16*256; idx += 256) {
    int row = idx >> 8, col = idx & 255;
    ShI[row*PSTR + col] = ws[OFF_SH + (nodeI0 + row)*256 + col];
    PJ [row*PSTR + col] = ws[OFF_P  + (nodeJ0 + row)*256 + col];
  }
  mtI[tid] = ws[OFF_MT + nodeI0*16 + tid];
  mtJ[tid] = ws[OFF_MT + nodeJ0*16 + tid];
  if (tid < 16) { ldI[tid] = ws[OFF_LD + nodeI0 + tid]; ldJ[tid] = ws[OFF_LD + nodeJ0 + tid]; }
  __syncthreads();

  const float4* si4 = (const float4*)&ShI[ti*PSTR];
  const float4* pj4 = (const float4*)&PJ[tj*PSTR];
  float tr = 0.f;
  #pragma unroll 16
  for (int t = 0; t < 64; ++t) {
    float4 xv = si4[t], yv = pj4[t];
    tr = fmaf(xv.x, yv.x, tr);
    tr = fmaf(xv.y, yv.y, tr);
    tr = fmaf(xv.z, yv.z, tr);
    tr = fmaf(xv.w, yv.w, tr);
  }

  const float* pj = &PJ[tj*PSTR];
  float d[16];
  #pragma unroll
  for (int k = 0; k < 16; ++k) d[k] = mtJ[tj*16+k] - mtI[ti*16+k];
  float mah = 0.f;
  #pragma unroll
  for (int k = 0; k < 16; ++k) {
    float acc = 0.f;
    #pragma unroll
    for (int ll = 0; ll < 16; ++ll) acc = fmaf(pj[k*16+ll], d[ll], acc);
    mah = fmaf(d[k], acc, mah);
  }

  float kl = 0.5f * (tr + mah - 16.f + ldJ[tj] - ldI[ti]);
  kl = fmaxf(kl, 0.f);
  int gi = by*16 + ti, gj = bx*16 + tj;
  float contrib = (gi == gj) ? 0.f : kl * beta[bz*65536 + gi*256 + gj];
  #pragma unroll
  for (int o = 32; o; o >>= 1) contrib += __shfl_down(contrib, o);
  __syncthreads();
  if ((tid & 63) == 0) red[tid >> 6] = contrib;
  __syncthreads();
  if (tid == 0) {
    ws[OFF_AP + (bz*16 + by)*16 + bx] = red[0] + red[1] + red[2] + red[3];
    unsigned old = __hip_atomic_fetch_add((unsigned*)(ws + OFF_CNT), 1u,
                                          __ATOMIC_ACQ_REL, __HIP_MEMORY_SCOPE_AGENT);
    lastflag = (old == 511u);
  }
  __syncthreads();

  if (lastflag) {
    // deterministic final reduce: fixed order, independent of which block is last
    double* dred = (double*)ShI;   // reuse LDS (align phase done)
    double v[2];
    #pragma unroll
    for (int b = 0; b < 2; ++b) {
      int row = b*256 + tid;
      float s = 0.f;
      #pragma unroll
      for (int c2 = 0; c2 < CE_CH; ++c2) s += ws[OFF_CEP + row*CE_CH + c2];
      int t = targets[row];
      float dt = 0.f;
      const float4* wt4 = (const float4*)(W + t*16);
      const float4* mr4 = (const float4*)(mu + row*16);
      #pragma unroll
      for (int j4 = 0; j4 < 4; ++j4) {
        float4 a = mr4[j4], bb = wt4[j4];
        dt = fmaf(a.x, bb.x, dt); dt = fmaf(a.y, bb.y, dt);
        dt = fmaf(a.z, bb.z, dt); dt = fmaf(a.w, bb.w, dt);
      }
      double ce = (double)logf(s) - (double)dt;
      v[b] = (double)ws[OFF_KLS + row] + (double)ws[OFF_AP + row] + ce;
    }
    for (int b = 0; b < 2; ++b) {
      dred[tid] = v[b];
      __syncthreads();
      for (int h = 128; h > 0; h >>= 1) {
        if (tid < h) dred[tid] += dred[tid + h];
        __syncthreads();
      }
      if (tid == 0) out[b] = (float)dred[0];
      __syncthreads();
    }
  }
}

extern "C" void kernel_launch(void* const* d_in, const int* in_sizes, int n_in,
                              void* d_out, int out_size, void* d_ws, size_t ws_size,
                              hipStream_t stream) {
  const float* mu          = (const float*)d_in[0];
  const float* Sigma       = (const float*)d_in[1];
  const float* phi         = (const float*)d_in[2];
  const float* mu_prior    = (const float*)d_in[3];
  const float* Sigma_prior = (const float*)d_in[4];
  const float* beta        = (const float*)d_in[5];
  const float* W_out       = (const float*)d_in[6];
  const float* gen         = (const float*)d_in[7];
  const int*   targets     = (const int*)d_in[8];
  float* out = (float*)d_out;
  float* ws  = (float*)d_ws;
  if (ws_size < (size_t)WS_FLOATS * sizeof(float)) return;  // fail loudly

  fusedA_kernel<<<256 + (NNODES/CE_ROWS)*CE_CH, 256, 0, stream>>>(
      mu, Sigma, phi, mu_prior, Sigma_prior, gen, W_out, ws);
  alignB_kernel<<<NB*16*16, 256, 0, stream>>>(beta, mu, W_out, targets, ws, out);
}